// Round 1
// baseline (71.656 us; speedup 1.0000x reference)
//
#include <hip/hip_runtime.h>

#define WW 512
#define HH 512
#define CC 64
#define HW (HH*WW)

// 3x3 inverse via adjugate (matches LU inverse to ~1e-7 rel for this K)
__device__ __forceinline__ void invert3(const float* __restrict__ m, float* o) {
    float a = m[0], b = m[1], c = m[2];
    float d = m[3], e = m[4], f = m[5];
    float g = m[6], h = m[7], i = m[8];
    float C11 =  (e*i - f*h);
    float C12 = -(d*i - f*g);
    float C13 =  (d*h - e*g);
    float C21 = -(b*i - c*h);
    float C22 =  (a*i - c*g);
    float C23 = -(a*h - b*g);
    float C31 =  (b*f - c*e);
    float C32 = -(a*f - c*d);
    float C33 =  (a*e - b*d);
    float det = a*C11 + b*C12 + c*C13;
    float id = 1.0f / det;
    o[0] = C11*id; o[1] = C21*id; o[2] = C31*id;
    o[3] = C12*id; o[4] = C22*id; o[5] = C32*id;
    o[6] = C13*id; o[7] = C23*id; o[8] = C33*id;
}

// reproject one point: pixel (px,py) of FROM cam with depth d -> normalized
// [-1,1] coords in TO cam. Mirrors reference reproject() op order in f32.
// cf/ct are [3,4] c2w row-major; Kinv is FROM intrinsics inverse; Kt is TO K.
__device__ __forceinline__ void reproj_pt(
    float px, float py, float d,
    const float Kinv[9],
    const float* __restrict__ cf, const float* __restrict__ ct,
    const float* __restrict__ Kt,
    float& ox, float& oy)
{
    // cam = Kinv @ [px,py,1] * d
    float cx = Kinv[0]*px + Kinv[1]*py + Kinv[2];
    float cy = Kinv[3]*px + Kinv[4]*py + Kinv[5];
    float cz = Kinv[6]*px + Kinv[7]*py + Kinv[8];
    cx *= d; cy *= d; cz *= d;
    // world = R_f @ cam + t_f
    float wx = cf[0]*cx + cf[1]*cy + cf[2]*cz + cf[3];
    float wy = cf[4]*cx + cf[5]*cy + cf[6]*cz + cf[7];
    float wz = cf[8]*cx + cf[9]*cy + cf[10]*cz + cf[11];
    // cam2 = R_t^T @ (world - t_t)
    float qx = wx - ct[3], qy = wy - ct[7], qz = wz - ct[11];
    float ax = ct[0]*qx + ct[4]*qy + ct[8]*qz;
    float ay = ct[1]*qx + ct[5]*qy + ct[9]*qz;
    float az = ct[2]*qx + ct[6]*qy + ct[10]*qz;
    // proj = K_t @ cam2
    float p0 = Kt[0]*ax + Kt[1]*ay + Kt[2]*az;
    float p1 = Kt[3]*ax + Kt[4]*ay + Kt[5]*az;
    float p2 = Kt[6]*ax + Kt[7]*ay + Kt[8]*az;
    float zs = (fabsf(p2) > 1e-6f) ? p2 : 1e-6f;
    float u = p0 / zs;
    float v = p1 / zs;
    ox = u / 512.0f * 2.0f - 1.0f;
    oy = v / 512.0f * 2.0f - 1.0f;
}

__global__ __launch_bounds__(256) void reproj_loss_kernel(
    const float* __restrict__ f1, const float* __restrict__ f2,
    const float* __restrict__ d1p, const float* __restrict__ d2p,
    const float* __restrict__ m1p,
    const float* __restrict__ K1, const float* __restrict__ K2,
    const float* __restrict__ cw1, const float* __restrict__ cw2,
    float* __restrict__ out)
{
    int gid = blockIdx.x * 256 + threadIdx.x;
    int j = gid & (WW - 1);
    int i = gid >> 9;

    float Ki1[9], Ki2[9];
    invert3(K1, Ki1);
    invert3(K2, Ki2);

    float px = j + 0.5f, py = i + 0.5f;

    // l1_2 at this pixel (cam1 -> cam2, depth1)
    float l12x, l12y;
    reproj_pt(px, py, d1p[gid], Ki1, cw1, cw2, K2, l12x, l12y);
    // l2_1 at this pixel (cam2 -> cam1, depth2)
    float l21x, l21y;
    reproj_pt(px, py, d2p[gid], Ki2, cw2, cw1, K1, l21x, l21y);

    // ---- bilinear setup at l1_2 (used for both l2_1-field sample and f1_2) ----
    float axf = (l12x + 1.0f) * 256.0f - 0.5f;
    float ayf = (l12y + 1.0f) * 256.0f - 0.5f;
    float ax0 = floorf(axf), ay0 = floorf(ayf);
    float awx = axf - ax0, awy = ayf - ay0;
    ax0 = fminf(fmaxf(ax0, -1e8f), 1e8f);
    ay0 = fminf(fmaxf(ay0, -1e8f), 1e8f);
    int ax0i = (int)ax0, ay0i = (int)ay0;

    float wA[4];
    int   offA[4];
    float vx = 0.0f, vy = 0.0f;   // l1_2_1 = sample of l2_1 field at l1_2
    #pragma unroll
    for (int k = 0; k < 4; ++k) {
        int dx = k & 1, dy = k >> 1;
        int ix = ax0i + dx, iy = ay0i + dy;
        float w = (dx ? awx : 1.0f - awx) * (dy ? awy : 1.0f - awy);
        bool valid = (ix >= 0) && (ix < WW) && (iy >= 0) && (iy < HH);
        if (valid) {
            int off = iy * WW + ix;
            wA[k] = w; offA[k] = off;
            // l2_1 at integer pixel (ix,iy): recompute from depth2[off]
            float cxv, cyv;
            reproj_pt(ix + 0.5f, iy + 0.5f, d2p[off], Ki2, cw2, cw1, K1, cxv, cyv);
            vx += w * cxv;
            vy += w * cyv;
        } else {
            wA[k] = 0.0f; offA[k] = 0;
        }
    }

    // dist1 = || l1 - l1_2_1 ||
    float gx = (j + 0.5f) / 512.0f * 2.0f - 1.0f;
    float gy = (i + 0.5f) / 512.0f * 2.0f - 1.0f;
    float ddx = gx - vx, ddy = gy - vy;
    float dist = sqrtf(ddx * ddx + ddy * ddy);
    float wgt = (dist < 0.0025f) ? m1p[gid] : 0.0f;

    float lsum = 0.0f;
    if (wgt != 0.0f) {
        // ---- bilinear setup at l2_1 (for f2_1 = sample features1 at l2_1) ----
        float bxf = (l21x + 1.0f) * 256.0f - 0.5f;
        float byf = (l21y + 1.0f) * 256.0f - 0.5f;
        float bx0 = floorf(bxf), by0 = floorf(byf);
        float bwx = bxf - bx0, bwy = byf - by0;
        bx0 = fminf(fmaxf(bx0, -1e8f), 1e8f);
        by0 = fminf(fmaxf(by0, -1e8f), 1e8f);
        int bx0i = (int)bx0, by0i = (int)by0;

        float wB[4];
        int   offB[4];
        #pragma unroll
        for (int k = 0; k < 4; ++k) {
            int dx = k & 1, dy = k >> 1;
            int ix = bx0i + dx, iy = by0i + dy;
            float w = (dx ? bwx : 1.0f - bwx) * (dy ? bwy : 1.0f - bwy);
            bool valid = (ix >= 0) && (ix < WW) && (iy >= 0) && (iy < HH);
            wB[k]  = valid ? w : 0.0f;
            offB[k] = valid ? (iy * WW + ix) : 0;
        }

        float acc = 0.0f;
        for (int c = 0; c < CC; ++c) {
            const float* F1 = f1 + c * HW;
            const float* F2 = f2 + c * HW;
            // f1 at identity grid == features1 exactly; f1_2 = bilinear(features2, l1_2)
            float s1 = F2[offA[0]]*wA[0] + F2[offA[1]]*wA[1]
                     + F2[offA[2]]*wA[2] + F2[offA[3]]*wA[3];
            float e1 = F1[gid] - s1;
            // f2 == features2 exactly; f2_1 = bilinear(features1, l2_1)
            float s2 = F1[offB[0]]*wB[0] + F1[offB[1]]*wB[1]
                     + F1[offB[2]]*wB[2] + F1[offB[3]]*wB[3];
            float e2 = F2[gid] - s2;
            acc += e1 * e1 + e2 * e2;
        }
        lsum = wgt * acc;
    }

    // block reduction: wave shuffle then LDS
    #pragma unroll
    for (int off = 32; off > 0; off >>= 1)
        lsum += __shfl_down(lsum, off);
    __shared__ float sred[4];
    if ((threadIdx.x & 63) == 0) sred[threadIdx.x >> 6] = lsum;
    __syncthreads();
    if (threadIdx.x == 0) {
        float t = (sred[0] + sred[1]) + (sred[2] + sred[3]);
        atomicAdd(out, t * (1.0f / 262144.0f));  // mean over B*1*H*W, LOSSFEATMULT=1
    }
}

extern "C" void kernel_launch(void* const* d_in, const int* in_sizes, int n_in,
                              void* d_out, int out_size, void* d_ws, size_t ws_size,
                              hipStream_t stream) {
    const float* f1  = (const float*)d_in[0];   // features1 [1,64,512,512]
    const float* f2  = (const float*)d_in[1];   // features2
    // d_in[2], d_in[3]: image1/image2 — unused by the reference loss
    const float* dp1 = (const float*)d_in[4];   // depth1 [1,1,512,512]
    const float* dp2 = (const float*)d_in[5];   // depth2
    const float* m1  = (const float*)d_in[6];   // mask1
    // d_in[7]: mask2 — unused
    const float* K1  = (const float*)d_in[8];   // [1,3,3]
    const float* K2  = (const float*)d_in[9];
    const float* c1  = (const float*)d_in[10];  // [1,3,4]
    const float* c2  = (const float*)d_in[11];

    float* out = (float*)d_out;
    hipMemsetAsync(out, 0, sizeof(float), stream);
    reproj_loss_kernel<<<HW / 256, 256, 0, stream>>>(
        f1, f2, dp1, dp2, m1, K1, K2, c1, c2, out);
}